// Round 6
// baseline (168.061 us; speedup 1.0000x reference)
//
#include <hip/hip_runtime.h>

typedef __attribute__((ext_vector_type(8))) short bf16x8;
typedef __attribute__((ext_vector_type(4))) float f32x4;

static __device__ __forceinline__ short f2bf(float f) {
    union { float f; unsigned u; } v; v.f = f;
    unsigned r = v.u + 0x7fffu + ((v.u >> 16) & 1u);
    return (short)(r >> 16);
}

// ---------------------------------------------------------------------------
// P: fused precompute.
//  blocks 0..63   : VT[c=(m23*8+r)][k2=(r02*64+n23)] bf16
//  blocks 64..127 : TL2[r02][m01][n01] bf16   (GEMM1 A, contiguous per r02)
// ---------------------------------------------------------------------------
__global__ __launch_bounds__(256) void ht_pre(const float* __restrict__ factors,
                                              const float* __restrict__ cores,
                                              short* __restrict__ TL2,
                                              short* __restrict__ VT) {
    const int bid = blockIdx.x, t = threadIdx.x;
    if (bid < 64) {
        __shared__ float TRl[64][9];
        const int m23 = bid;
        const int m2 = m23 >> 3, m3 = m23 & 7;
        {   // TR slice for this m23: TRl[n23][r24]
            const int v = t * 2;
            const int n23 = v >> 3;
            const int r24 = v & 7;            // even
            const int n2 = n23 >> 3, n3 = n23 & 7;
            const float* f2p = factors + 1024 + n2 * 64 + m2 * 8;
            const float* f3p = factors + 1536 + n3 * 64 + m3 * 8;
            const float* c2p = cores + 1024;
            float s0 = 0.f, s1 = 0.f;
            #pragma unroll
            for (int r23 = 0; r23 < 8; ++r23) {
                float a = f2p[r23];
                #pragma unroll
                for (int r34 = 0; r34 < 8; ++r34) {
                    float wv = a * f3p[r34];
                    s0 += wv * c2p[r23 * 64 + r34 * 8 + r24];
                    s1 += wv * c2p[r23 * 64 + r34 * 8 + r24 + 1];
                }
            }
            TRl[n23][r24] = s0;
            TRl[n23][r24 + 1] = s1;
        }
        __syncthreads();
        {   // VT rows c = m23*8 + r ; thread covers 16 consecutive k2
            const int r = t >> 5, seg = t & 31;
            const int k2b = seg * 16;
            const int r02 = k2b >> 6;
            float c0v[8];
            #pragma unroll
            for (int r24 = 0; r24 < 8; ++r24)
                c0v[r24] = cores[r02 * 64 + r24 * 8 + r];
            short ov[16];
            #pragma unroll
            for (int j = 0; j < 16; ++j) {
                const int n23 = (k2b + j) & 63;
                float s = 0.f;
                #pragma unroll
                for (int r24 = 0; r24 < 8; ++r24)
                    s += TRl[n23][r24] * c0v[r24];
                ov[j] = f2bf(s);
            }
            short* dst = VT + (m23 * 8 + r) * 512 + k2b;
            *(bf16x8*)dst = *(bf16x8*)&ov[0];
            *(bf16x8*)(dst + 8) = *(bf16x8*)&ov[8];
        }
    } else {
        const int idx = ((bid - 64) * 256 + t) * 2;
        const int p = idx >> 6, n01 = idx & 63;   // n01 even
        const int n0 = n01 >> 3, n1 = n01 & 7;
        const int mm = p >> 3, r02 = p & 7;
        const int m0 = mm >> 3, m1 = mm & 7;
        const float* f0 = factors + n0 * 64 + m0 * 8;
        const float* f1a = factors + 512 + n1 * 64 + m1 * 8;
        const float* f1b = f1a + 64;
        const float* c1 = cores + 512;
        float s0 = 0.f, s1 = 0.f;
        #pragma unroll
        for (int r01 = 0; r01 < 8; ++r01) {
            float a = f0[r01];
            #pragma unroll
            for (int r12 = 0; r12 < 8; ++r12) {
                float cv = c1[r01 * 64 + r12 * 8 + r02];
                s0 += a * f1a[r12] * cv;
                s1 += a * f1b[r12] * cv;
            }
        }
        unsigned w0 = (unsigned short)f2bf(s0);
        unsigned w1 = (unsigned short)f2bf(s1);
        *(unsigned*)&TL2[r02 * 4096 + mm * 64 + n01] = w0 | (w1 << 16);
    }
}

// ---------------------------------------------------------------------------
// Fused main: block = (b, col-quarter). Per r02 slice:
//   GEMM1: Y[64 m01][64 n23] = TL2[r02] (64x64) * X_b (64x64)   -> LDS (dbuf)
//   GEMM2: C[64 m01][128 c] += Y * VT[cols][r02-slice]          (B from L2)
// One barrier per r02; VT B-frags prefetched one slice ahead.
// ---------------------------------------------------------------------------
__global__ __launch_bounds__(256, 4) void ht_fused(const float* __restrict__ x,
                                                   const short* __restrict__ TL2,
                                                   const short* __restrict__ VT,
                                                   float* __restrict__ out) {
    __shared__ short XT[64 * 64];      // X^T[n23][n01], swizzled, 8 KB
    __shared__ short Y[2][64 * 64];    // Y[m01][n23], swizzled, 2 x 8 KB

    const int t = threadIdx.x;
    const int bid = blockIdx.x;
    const int b = bid >> 2;
    const int cq = bid & 3;
    const int w = t >> 6, l = t & 63;
    const int lr = l & 15, lk = l >> 4;

    // ---- phase 1: load x_b, convert bf16, transpose into XT (swizzled)
    {
        const float* xb = x + b * 4096;
        #pragma unroll
        for (int j = 0; j < 4; ++j) {
            f32x4 v = *(const f32x4*)(xb + j * 1024 + t * 4);
            int n01 = j * 16 + (t >> 4);
            int rbase = (t & 15) * 4;
            #pragma unroll
            for (int e = 0; e < 4; ++e) {
                int rr = rbase + e;   // n23
                XT[rr * 64 + (n01 ^ ((rr & 7) << 3))] = f2bf(v[e]);
            }
        }
    }
    __syncthreads();

    // GEMM1 B-frags (X): wave owns n23-tile nt = w. Fixed for whole kernel.
    bf16x8 bx[2];
    #pragma unroll
    for (int kh = 0; kh < 2; ++kh) {
        int rr = w * 16 + lr;                       // n23 (B col)
        int g = (kh * 4 + lk) ^ (rr & 7);           // n01 granule, swizzled
        bx[kh] = *(const bf16x8*)&XT[rr * 64 + g * 8];
    }

    // GEMM1: slice r02 -> Y[buf]
    auto gemm1 = [&](int r02, int buf) {
        const short* tl = TL2 + r02 * 4096;
        #pragma unroll
        for (int mt = 0; mt < 4; ++mt) {
            f32x4 d = {0.f, 0.f, 0.f, 0.f};
            #pragma unroll
            for (int kh = 0; kh < 2; ++kh) {
                bf16x8 a1 = *(const bf16x8*)&tl[(mt * 16 + lr) * 64 + kh * 32 + lk * 8];
                d = __builtin_amdgcn_mfma_f32_16x16x32_bf16(a1, bx[kh], d, 0, 0, 0);
            }
            #pragma unroll
            for (int reg = 0; reg < 4; ++reg) {
                int row = mt * 16 + lk * 4 + reg;   // m01
                int col = w * 16 + lr;              // n23
                int g = ((col >> 3) ^ (row & 7));
                Y[buf][row * 64 + g * 8 + (col & 7)] = f2bf(d[reg]);
            }
        }
    };

    // VT B-frag loads for slice r02 (wave owns 32 cols)
    const int cbase = cq * 128 + w * 32;
    auto load_bfr = [&](int r02, bf16x8 bfr[2][2]) {
        #pragma unroll
        for (int ctl = 0; ctl < 2; ++ctl) {
            const short* vp = VT + (cbase + ctl * 16 + lr) * 512 + r02 * 64;
            #pragma unroll
            for (int kh = 0; kh < 2; ++kh)
                bfr[ctl][kh] = *(const bf16x8*)&vp[kh * 32 + lk * 8];
        }
    };

    f32x4 acc[4][2];
    #pragma unroll
    for (int rt = 0; rt < 4; ++rt)
        #pragma unroll
        for (int ctl = 0; ctl < 2; ++ctl)
            acc[rt][ctl] = (f32x4){0.f, 0.f, 0.f, 0.f};

    bf16x8 bcur[2][2], bnxt[2][2];
    load_bfr(0, bcur);
    gemm1(0, 0);
    __syncthreads();

    #pragma unroll
    for (int r02 = 0; r02 < 8; ++r02) {
        const int buf = r02 & 1;
        if (r02 < 7) {
            load_bfr(r02 + 1, bnxt);
            gemm1(r02 + 1, buf ^ 1);
        }
        // GEMM2 partial: C += Y[buf] * V_slice
        #pragma unroll
        for (int rt = 0; rt < 4; ++rt) {
            #pragma unroll
            for (int kh = 0; kh < 2; ++kh) {
                int row = rt * 16 + lr;             // m01 (A row)
                int g = (kh * 4 + lk) ^ (row & 7);
                bf16x8 af = *(const bf16x8*)&Y[buf][row * 64 + g * 8];
                #pragma unroll
                for (int ctl = 0; ctl < 2; ++ctl)
                    acc[rt][ctl] = __builtin_amdgcn_mfma_f32_16x16x32_bf16(af, bcur[ctl][kh], acc[rt][ctl], 0, 0, 0);
            }
        }
        __syncthreads();
        #pragma unroll
        for (int ctl = 0; ctl < 2; ++ctl)
            #pragma unroll
            for (int kh = 0; kh < 2; ++kh)
                bcur[ctl][kh] = bnxt[ctl][kh];
    }

    // ---- epilogue: plain stores (round-1 evidence: exact 64 MB WRITE)
    float* ob = out + b * 32768 + cbase;
    #pragma unroll
    for (int rt = 0; rt < 4; ++rt)
        #pragma unroll
        for (int ctl = 0; ctl < 2; ++ctl)
            #pragma unroll
            for (int reg = 0; reg < 4; ++reg)
                ob[(rt * 16 + lk * 4 + reg) * 512 + ctl * 16 + lr] = acc[rt][ctl][reg];
}

extern "C" void kernel_launch(void* const* d_in, const int* in_sizes, int n_in,
                              void* d_out, int out_size, void* d_ws, size_t ws_size,
                              hipStream_t stream) {
    const float* x       = (const float*)d_in[0];   // (512,8,8,8,8)
    const float* factors = (const float*)d_in[1];   // (4,8,8,8)
    const float* cores   = (const float*)d_in[2];   // (3,8,8,8)
    float* out = (float*)d_out;                     // (512,8,8,8,8,8)

    short* TL2 = (short*)d_ws;           // 32768  bf16 (64 KB)
    short* VT  = TL2 + 32768;            // 262144 bf16 (512 KB)

    hipLaunchKernelGGL(ht_pre, dim3(128), dim3(256), 0, stream, factors, cores, TL2, VT);
    hipLaunchKernelGGL(ht_fused, dim3(2048), dim3(256), 0, stream, x, TL2, VT, out);
}

// Round 11
// 125.909 us; speedup vs baseline: 1.3348x; 1.3348x over previous
//
#include <hip/hip_runtime.h>

typedef __attribute__((ext_vector_type(8))) short bf16x8;
typedef __attribute__((ext_vector_type(4))) float f32x4;

static __device__ __forceinline__ short f2bf(float f) {
    union { float f; unsigned u; } v; v.f = f;
    unsigned r = v.u + 0x7fffu + ((v.u >> 16) & 1u);
    return (short)(r >> 16);
}

// ---------------------------------------------------------------------------
// P: fused precompute, outputs in MFMA FRAG ORDER.
//  VTF: B-frags of V^T. elem(ct16,kb,l,e) = V^T[c=ct16*16+(l&15)][k2=kb*32+(l>>4)*8+e]
//       flat idx = (ct16*16+kb)*512 + l*8 + e       (262144 shorts)
//  TLTF: A-frags of T_L^T. elem(p16,half,l,e) = TL[p=p16*16+(l&15)][n01=half*32+(l>>4)*8+e]
//       flat idx = (p16*2+half)*512 + l*8 + e       (32768 shorts)
// ---------------------------------------------------------------------------
__global__ __launch_bounds__(256) void ht_pre(const float* __restrict__ factors,
                                              const float* __restrict__ cores,
                                              short* __restrict__ TLTF,
                                              short* __restrict__ VTF) {
    const int bid = blockIdx.x, t = threadIdx.x;
    if (bid < 64) {
        __shared__ float TRl[64][9];
        const int m23 = bid;
        const int m2 = m23 >> 3, m3 = m23 & 7;
        {   // TR slice for this m23: TRl[n23][r24]
            const int v = t * 2;
            const int n23 = v >> 3;
            const int r24 = v & 7;            // even
            const int n2 = n23 >> 3, n3 = n23 & 7;
            const float* f2p = factors + 1024 + n2 * 64 + m2 * 8;
            const float* f3p = factors + 1536 + n3 * 64 + m3 * 8;
            const float* c2p = cores + 1024;
            float s0 = 0.f, s1 = 0.f;
            #pragma unroll
            for (int r23 = 0; r23 < 8; ++r23) {
                float a = f2p[r23];
                #pragma unroll
                for (int r34 = 0; r34 < 8; ++r34) {
                    float wv = a * f3p[r34];
                    s0 += wv * c2p[r23 * 64 + r34 * 8 + r24];
                    s1 += wv * c2p[r23 * 64 + r34 * 8 + r24 + 1];
                }
            }
            TRl[n23][r24] = s0;
            TRl[n23][r24 + 1] = s1;
        }
        __syncthreads();
        {   // V^T row c = m23*8 + r ; thread covers 16 consecutive k2
            const int r = t >> 5, seg = t & 31;
            const int k2b = seg * 16;
            const int r02 = k2b >> 6;
            float c0v[8];
            #pragma unroll
            for (int r24 = 0; r24 < 8; ++r24)
                c0v[r24] = cores[r02 * 64 + r24 * 8 + r];
            short ov[16];
            #pragma unroll
            for (int j = 0; j < 16; ++j) {
                const int n23 = (k2b + j) & 63;
                float s = 0.f;
                #pragma unroll
                for (int r24 = 0; r24 < 8; ++r24)
                    s += TRl[n23][r24] * c0v[r24];
                ov[j] = f2bf(s);
            }
            const int c = m23 * 8 + r;
            const int ct16 = c >> 4, lrow = c & 15;
            const int kb = k2b >> 5;
            const int hi0 = (k2b >> 3) & 3;
            const int base = (ct16 * 16 + kb) * 512 + lrow * 8;
            *(bf16x8*)&VTF[base + hi0 * 128]       = *(bf16x8*)&ov[0];
            *(bf16x8*)&VTF[base + (hi0 + 1) * 128] = *(bf16x8*)&ov[8];
        }
    } else {
        const int idx = ((bid - 64) * 256 + t) * 2;
        const int p = idx >> 6, n01 = idx & 63;   // n01 even
        const int n0 = n01 >> 3, n1 = n01 & 7;
        const int mm = p >> 3, r02 = p & 7;
        const int m0 = mm >> 3, m1 = mm & 7;
        const float* f0 = factors + n0 * 64 + m0 * 8;
        const float* f1a = factors + 512 + n1 * 64 + m1 * 8;
        const float* f1b = f1a + 64;
        const float* c1 = cores + 512;
        float s0 = 0.f, s1 = 0.f;
        #pragma unroll
        for (int r01 = 0; r01 < 8; ++r01) {
            float a = f0[r01];
            #pragma unroll
            for (int r12 = 0; r12 < 8; ++r12) {
                float cv = c1[r01 * 64 + r12 * 8 + r02];
                s0 += a * f1a[r12] * cv;
                s1 += a * f1b[r12] * cv;
            }
        }
        unsigned w0 = (unsigned short)f2bf(s0);
        unsigned w1 = (unsigned short)f2bf(s1);
        const int p16 = p >> 4, prow = p & 15;
        const int half = n01 >> 5, hi = (n01 >> 3) & 3, e = n01 & 7;
        *(unsigned*)&TLTF[(p16 * 2 + half) * 512 + (hi * 16 + prow) * 8 + e] = w0 | (w1 << 16);
    }
}

// ---------------------------------------------------------------------------
// Main: one block per batch b. 3 phases, 2 barriers.
//  P1: x_b -> bf16 -> XT LDS (transposed, swizzled)
//  P2: GEMM1 Y[512 p][64 n23] = TLT*X ; write Y into YF LDS in FRAG ORDER
//  P3: GEMM2 C[64 m01][512 c] = Y * V, VTF coalesced B-frags, depth-1 dbuf
// ---------------------------------------------------------------------------
__global__ __launch_bounds__(256, 2) void ht_main(const float* __restrict__ x,
                                                  const short* __restrict__ TLTF,
                                                  const short* __restrict__ VTF,
                                                  float* __restrict__ out) {
    __shared__ short XT[64 * 64];     // 8 KB
    __shared__ short YF[64 * 512];    // 64 KB, frag-order: (rt*16+kb)*512 + l*8 + e

    const int t = threadIdx.x;
    const int b = blockIdx.x;
    const int w = t >> 6, l = t & 63;
    const int lr = l & 15, lk = l >> 4;

    // ---- phase 1
    {
        const float* xb = x + b * 4096;
        #pragma unroll
        for (int j = 0; j < 4; ++j) {
            f32x4 v = *(const f32x4*)(xb + j * 1024 + t * 4);
            int n01 = j * 16 + (t >> 4);
            int rbase = (t & 15) * 4;
            #pragma unroll
            for (int e = 0; e < 4; ++e) {
                int rr = rbase + e;   // n23
                XT[rr * 64 + (n01 ^ ((rr & 7) << 3))] = f2bf(v[e]);
            }
        }
    }
    __syncthreads();

    // ---- phase 2: GEMM1, wave w owns p-rows [w*128, w*128+128)
    {
        bf16x8 bx[4][2];
        #pragma unroll
        for (int ct = 0; ct < 4; ++ct) {
            int rr = ct * 16 + lr;
            #pragma unroll
            for (int kh = 0; kh < 2; ++kh)
                bx[ct][kh] = *(const bf16x8*)&XT[rr * 64 + (((kh * 4 + lk) ^ (rr & 7))) * 8];
        }
        #pragma unroll
        for (int pt = 0; pt < 8; ++pt) {
            const short* ap = TLTF + (w * 8 + pt) * 1024 + l * 8;
            bf16x8 a0 = *(const bf16x8*)ap;
            bf16x8 a1 = *(const bf16x8*)(ap + 512);
            #pragma unroll
            for (int ct = 0; ct < 4; ++ct) {
                f32x4 d = {0.f, 0.f, 0.f, 0.f};
                d = __builtin_amdgcn_mfma_f32_16x16x32_bf16(a0, bx[ct][0], d, 0, 0, 0);
                d = __builtin_amdgcn_mfma_f32_16x16x32_bf16(a1, bx[ct][1], d, 0, 0, 0);
                #pragma unroll
                for (int reg = 0; reg < 4; ++reg) {
                    int pl = lk * 4 + reg;                    // p & 15 (low bits)
                    int m_lo = pt * 2 + (pl >> 3);            // m01 & 15 (rt = w)
                    int k2 = (pl & 7) * 64 + ct * 16 + lr;
                    int kb = k2 >> 5, hi = (k2 >> 3) & 3, e = k2 & 7;
                    YF[(w * 16 + kb) * 512 + (hi * 16 + m_lo) * 8 + e] = f2bf(d[reg]);
                }
            }
        }
    }
    __syncthreads();

    // ---- phase 3: GEMM2, wave w owns cols [w*128, w*128+128)
    {
        f32x4 acc[4][8];
        #pragma unroll
        for (int rt = 0; rt < 4; ++rt)
            #pragma unroll
            for (int ctl = 0; ctl < 8; ++ctl)
                acc[rt][ctl] = (f32x4){0.f, 0.f, 0.f, 0.f};

        bf16x8 afA[4], afB[4], bvA[8], bvB[8];

        #define LDA(kb, af_)  { _Pragma("unroll") \
            for (int rt = 0; rt < 4; ++rt) \
                af_[rt] = *(const bf16x8*)&YF[(rt * 16 + (kb)) * 512 + l * 8]; }
        #define LDB(kb, bv_)  { _Pragma("unroll") \
            for (int ctl = 0; ctl < 8; ++ctl) \
                bv_[ctl] = *(const bf16x8*)&VTF[((w * 8 + ctl) * 16 + (kb)) * 512 + l * 8]; }
        #define MM(af_, bv_)  { _Pragma("unroll") \
            for (int rt = 0; rt < 4; ++rt) { _Pragma("unroll") \
                for (int ctl = 0; ctl < 8; ++ctl) \
                    acc[rt][ctl] = __builtin_amdgcn_mfma_f32_16x16x32_bf16(af_[rt], bv_[ctl], acc[rt][ctl], 0, 0, 0); } }

        LDA(0, afA); LDB(0, bvA);
        #pragma unroll
        for (int kp = 0; kp < 8; ++kp) {
            LDA(kp * 2 + 1, afB); LDB(kp * 2 + 1, bvB);
            MM(afA, bvA);
            if (kp < 7) { LDA(kp * 2 + 2, afA); LDB(kp * 2 + 2, bvA); }
            MM(afB, bvB);
        }
        #undef LDA
        #undef LDB
        #undef MM

        float* ob = out + b * 32768 + w * 128;
        #pragma unroll
        for (int rt = 0; rt < 4; ++rt)
            #pragma unroll
            for (int ctl = 0; ctl < 8; ++ctl)
                #pragma unroll
                for (int reg = 0; reg < 4; ++reg)
                    ob[(rt * 16 + lk * 4 + reg) * 512 + ctl * 16 + lr] = acc[rt][ctl][reg];
    }
}

extern "C" void kernel_launch(void* const* d_in, const int* in_sizes, int n_in,
                              void* d_out, int out_size, void* d_ws, size_t ws_size,
                              hipStream_t stream) {
    const float* x       = (const float*)d_in[0];   // (512,8,8,8,8)
    const float* factors = (const float*)d_in[1];   // (4,8,8,8)
    const float* cores   = (const float*)d_in[2];   // (3,8,8,8)
    float* out = (float*)d_out;                     // (512,8,8,8,8,8)

    short* TLTF = (short*)d_ws;          // 32768  bf16 (64 KB)
    short* VTF  = TLTF + 32768;          // 262144 bf16 (512 KB)

    hipLaunchKernelGGL(ht_pre, dim3(128), dim3(256), 0, stream, factors, cores, TLTF, VTF);
    hipLaunchKernelGGL(ht_main, dim3(512), dim3(256), 0, stream, x, TLTF, VTF, out);
}

// Round 13
// 102.427 us; speedup vs baseline: 1.6408x; 1.2293x over previous
//
#include <hip/hip_runtime.h>

typedef __attribute__((ext_vector_type(8))) short bf16x8;
typedef __attribute__((ext_vector_type(4))) float f32x4;

struct u32x2 { unsigned x, y; };

static __device__ __forceinline__ short f2bf(float f) {
    union { float f; unsigned u; } v; v.f = f;
    unsigned r = v.u + 0x7fffu + ((v.u >> 16) & 1u);
    return (short)(r >> 16);
}

// ---------------------------------------------------------------------------
// P: fused precompute, outputs in MFMA FRAG ORDER. K2 ORDER: k2' = n23*8 + r02.
//  VTF: B-frags of V^T. layout: (ct16*16+kb)*512 + (l>>4)*128 + (l&15)*8 + e
//       where row c = ct16*16+(l&15), k2' = kb*32 + (l>>4)*8 + e   (262144 shorts)
//  TLTF: A-frags of T_L^T: (p16*2+half)*512 + (hi*16+prow)*8 + e   (32768 shorts)
// ---------------------------------------------------------------------------
__global__ __launch_bounds__(256) void ht_pre(const float* __restrict__ factors,
                                              const float* __restrict__ cores,
                                              short* __restrict__ TLTF,
                                              short* __restrict__ VTF) {
    const int bid = blockIdx.x, t = threadIdx.x;
    if (bid < 64) {
        __shared__ float TRl[64][9];
        const int m23 = bid;
        const int m2 = m23 >> 3, m3 = m23 & 7;
        {   // TR slice for this m23: TRl[n23][r24]
            const int v = t * 2;
            const int n23 = v >> 3;
            const int r24 = v & 7;            // even
            const int n2 = n23 >> 3, n3 = n23 & 7;
            const float* f2p = factors + 1024 + n2 * 64 + m2 * 8;
            const float* f3p = factors + 1536 + n3 * 64 + m3 * 8;
            const float* c2p = cores + 1024;
            float s0 = 0.f, s1 = 0.f;
            #pragma unroll
            for (int r23 = 0; r23 < 8; ++r23) {
                float a = f2p[r23];
                #pragma unroll
                for (int r34 = 0; r34 < 8; ++r34) {
                    float wv = a * f3p[r34];
                    s0 += wv * c2p[r23 * 64 + r34 * 8 + r24];
                    s1 += wv * c2p[r23 * 64 + r34 * 8 + r24 + 1];
                }
            }
            TRl[n23][r24] = s0;
            TRl[n23][r24 + 1] = s1;
        }
        __syncthreads();
        {   // V rows in k2' order: thread covers k2' in [seg*16, seg*16+16)
            const int r = t >> 5, seg = t & 31;
            short ov[16];
            #pragma unroll
            for (int j = 0; j < 16; ++j) {
                const int n23 = seg * 2 + (j >> 3);
                const int r02 = j & 7;
                float s = 0.f;
                #pragma unroll
                for (int r24 = 0; r24 < 8; ++r24)
                    s += TRl[n23][r24] * cores[r02 * 64 + r24 * 8 + r];
                ov[j] = f2bf(s);
            }
            const int c = m23 * 8 + r;
            const int ct16 = c >> 4, lrow = c & 15;
            const int kb = seg >> 1;             // k2' block of 32
            const int hi0 = (seg * 2) & 3;       // octet index within kb
            const int base = (ct16 * 16 + kb) * 512 + lrow * 8;
            *(bf16x8*)&VTF[base + hi0 * 128]       = *(bf16x8*)&ov[0];
            *(bf16x8*)&VTF[base + (hi0 + 1) * 128] = *(bf16x8*)&ov[8];
        }
    } else {
        const int idx = ((bid - 64) * 256 + t) * 2;
        const int p = idx >> 6, n01 = idx & 63;   // n01 even
        const int n0 = n01 >> 3, n1 = n01 & 7;
        const int mm = p >> 3, r02 = p & 7;
        const int m0 = mm >> 3, m1 = mm & 7;
        const float* f0 = factors + n0 * 64 + m0 * 8;
        const float* f1a = factors + 512 + n1 * 64 + m1 * 8;
        const float* f1b = f1a + 64;
        const float* c1 = cores + 512;
        float s0 = 0.f, s1 = 0.f;
        #pragma unroll
        for (int r01 = 0; r01 < 8; ++r01) {
            float a = f0[r01];
            #pragma unroll
            for (int r12 = 0; r12 < 8; ++r12) {
                float cv = c1[r01 * 64 + r12 * 8 + r02];
                s0 += a * f1a[r12] * cv;
                s1 += a * f1b[r12] * cv;
            }
        }
        unsigned w0 = (unsigned short)f2bf(s0);
        unsigned w1 = (unsigned short)f2bf(s1);
        const int p16 = p >> 4, prow = p & 15;
        const int half = n01 >> 5, hi = (n01 >> 3) & 3, e = n01 & 7;
        *(unsigned*)&TLTF[(p16 * 2 + half) * 512 + (hi * 16 + prow) * 8 + e] = w0 | (w1 << 16);
    }
}

// ---------------------------------------------------------------------------
// Main: one block per batch b, 512 threads (8 waves). 3 phases, 2 barriers.
//  P1: x_b -> bf16 -> XT LDS (transposed, swizzled)
//  P2: GEMM1; lane's 4 outputs are 4 consecutive k2' -> ONE ds_write_b64
//      into YS[m01][k2'] (octet-XOR swizzled)
//  P3: GEMM2 C[64][512] = Y * V; af via conflict-free ds_read_b128,
//      bv via coalesced frag-order global loads. acc[4][4] (no spill).
// ---------------------------------------------------------------------------
__global__ __launch_bounds__(512, 2) void ht_main(const float* __restrict__ x,
                                                  const short* __restrict__ TLTF,
                                                  const short* __restrict__ VTF,
                                                  float* __restrict__ out) {
    __shared__ short XT[64 * 64];     // 8 KB
    __shared__ short YS[64 * 512];    // 64 KB: m01*512 + ((k2'>>3) ^ (m01&7))*8 + (k2'&7)

    const int t = threadIdx.x;
    const int b = blockIdx.x;
    const int w = t >> 6, l = t & 63;
    const int lr = l & 15, lk = l >> 4;

    // ---- phase 1: load x_b, convert bf16, transpose into XT (swizzled)
    {
        const float* xb = x + b * 4096;
        #pragma unroll
        for (int j = 0; j < 2; ++j) {
            f32x4 v = *(const f32x4*)(xb + j * 2048 + t * 4);
            int n01 = j * 32 + (t >> 4);
            int rbase = (t & 15) * 4;
            #pragma unroll
            for (int e = 0; e < 4; ++e) {
                int rr = rbase + e;   // n23
                XT[rr * 64 + (n01 ^ ((rr & 7) << 3))] = f2bf(v[e]);
            }
        }
    }
    __syncthreads();

    // ---- phase 2: GEMM1, wave w owns p16 tiles [w*4, w*4+4)
    {
        bf16x8 bx[4][2];
        #pragma unroll
        for (int ct = 0; ct < 4; ++ct) {
            int rr = ct * 16 + lr;
            #pragma unroll
            for (int kh = 0; kh < 2; ++kh)
                bx[ct][kh] = *(const bf16x8*)&XT[rr * 64 + ((kh * 4 + lk) ^ (rr & 7)) * 8];
        }
        #pragma unroll
        for (int pt = 0; pt < 4; ++pt) {
            const short* ap = TLTF + (w * 4 + pt) * 1024 + l * 8;
            bf16x8 a0 = *(const bf16x8*)ap;
            bf16x8 a1 = *(const bf16x8*)(ap + 512);
            const int row = w * 8 + pt * 2 + (lk >> 1);        // m01
            #pragma unroll
            for (int ct = 0; ct < 4; ++ct) {
                f32x4 d = {0.f, 0.f, 0.f, 0.f};
                d = __builtin_amdgcn_mfma_f32_16x16x32_bf16(a0, bx[ct][0], d, 0, 0, 0);
                d = __builtin_amdgcn_mfma_f32_16x16x32_bf16(a1, bx[ct][1], d, 0, 0, 0);
                const int n23 = ct * 16 + lr;
                // k2' = n23*8 + (lk&1)*4 + reg  -> 4 consecutive shorts, one b64
                unsigned lo = (unsigned short)f2bf(d[0]) | ((unsigned)(unsigned short)f2bf(d[1]) << 16);
                unsigned hi = (unsigned short)f2bf(d[2]) | ((unsigned)(unsigned short)f2bf(d[3]) << 16);
                u32x2 val; val.x = lo; val.y = hi;
                *(u32x2*)&YS[row * 512 + (n23 ^ (row & 7)) * 8 + (lk & 1) * 4] = val;
            }
        }
    }
    __syncthreads();

    // ---- phase 3: GEMM2, wave w owns cols [w*64, w*64+64)
    {
        f32x4 acc[4][4];
        #pragma unroll
        for (int rt = 0; rt < 4; ++rt)
            #pragma unroll
            for (int ctl = 0; ctl < 4; ++ctl)
                acc[rt][ctl] = (f32x4){0.f, 0.f, 0.f, 0.f};

        #pragma unroll
        for (int kb = 0; kb < 16; ++kb) {
            bf16x8 bv[4];
            #pragma unroll
            for (int ctl = 0; ctl < 4; ++ctl)
                bv[ctl] = *(const bf16x8*)&VTF[((w * 4 + ctl) * 16 + kb) * 512 + l * 8];
            bf16x8 af[4];
            #pragma unroll
            for (int rt = 0; rt < 4; ++rt) {
                const int row = rt * 16 + lr;
                af[rt] = *(const bf16x8*)&YS[row * 512 + ((kb * 4 + lk) ^ (lr & 7)) * 8];
            }
            #pragma unroll
            for (int rt = 0; rt < 4; ++rt)
                #pragma unroll
                for (int ctl = 0; ctl < 4; ++ctl)
                    acc[rt][ctl] = __builtin_amdgcn_mfma_f32_16x16x32_bf16(af[rt], bv[ctl], acc[rt][ctl], 0, 0, 0);
        }

        float* ob = out + b * 32768 + w * 64;
        #pragma unroll
        for (int rt = 0; rt < 4; ++rt)
            #pragma unroll
            for (int ctl = 0; ctl < 4; ++ctl)
                #pragma unroll
                for (int reg = 0; reg < 4; ++reg)
                    ob[(rt * 16 + lk * 4 + reg) * 512 + ctl * 16 + lr] = acc[rt][ctl][reg];
    }
}

extern "C" void kernel_launch(void* const* d_in, const int* in_sizes, int n_in,
                              void* d_out, int out_size, void* d_ws, size_t ws_size,
                              hipStream_t stream) {
    const float* x       = (const float*)d_in[0];   // (512,8,8,8,8)
    const float* factors = (const float*)d_in[1];   // (4,8,8,8)
    const float* cores   = (const float*)d_in[2];   // (3,8,8,8)
    float* out = (float*)d_out;                     // (512,8,8,8,8,8)

    short* TLTF = (short*)d_ws;          // 32768  bf16 (64 KB)
    short* VTF  = TLTF + 32768;          // 262144 bf16 (512 KB)

    hipLaunchKernelGGL(ht_pre, dim3(128), dim3(256), 0, stream, factors, cores, TLTF, VTF);
    hipLaunchKernelGGL(ht_main, dim3(512), dim3(512), 0, stream, x, TLTF, VTF, out);
}